// Round 3
// baseline (119.821 us; speedup 1.0000x reference)
//
#include <hip/hip_runtime.h>

// FwFM second-order interaction.
// Identity: v^T S v == v^T W v for S = 0.5(W+W^T), diag(S) = diag(W), so
//   out[b,d] = sum_{k<l} 0.5*(W[k,l]+W[l,k]) * x[k,b,d]*x[l,b,d]   (741 pairs, K=39)
//
// Shapes: x [39, 8192, 64] f32, W [39,39] f32, out [8192,64] f32.
// Memory floor: ~84 MB traffic -> ~13.6 us at 6.3 TB/s achievable.
// NOTE: dur_us includes ~79 us of harness reset (327 MB ws poison + 84 MB
// input restore) visible as fillBufferAligned in rocprof — not ours.
//
// R3 vs R2 (~36 us kernel-side): 1 float/thread instead of float2.
//  - v[39] = 39 VGPR (was 78) -> total ~55, far from any spill cliff.
//  - waves_per_eu(6,8): RA budget ~84 regs, occupancy 24-32 waves/CU (was <=20).
//  - loads stay coalesced: 64 lanes x 4 B = 256 B contiguous per field.

#define KF 39
#define NPAIR (KF * (KF - 1) / 2)   // 741
#define NELEM (8192 * 64)           // B*D = 524288 output elements

// Tiny precompute: c[p] = 0.5*(W[k,l]+W[l,k]) for l<k, p = k(k-1)/2 + l.
// Contiguous pair order -> main kernel's uniform reads batch into s_load_dwordx16.
__global__ void fwfm_coef_kernel(const float* __restrict__ W, float* __restrict__ c) {
    const int t = blockIdx.x * 256 + threadIdx.x;   // over K*K = 1521
    if (t >= KF * KF) return;
    const int k = t / KF;
    const int l = t - k * KF;
    if (l < k) {
        c[(k * (k - 1)) / 2 + l] = 0.5f * (W[k * KF + l] + W[l * KF + k]);
    }
}

__global__ __attribute__((amdgpu_flat_work_group_size(256, 256), amdgpu_waves_per_eu(6, 8)))
void fwfm_kernel(const float* __restrict__ x,
                 const float* __restrict__ c,
                 float* __restrict__ out) {
    const int n = blockIdx.x * 256 + threadIdx.x;   // element index in [0, NELEM)

    // 39 coalesced dword loads; all independent, issued before first use.
    float v[KF];
#pragma unroll
    for (int k = 0; k < KF; ++k) {
        v[k] = x[(size_t)k * NELEM + n];
    }

    // Pair loop in coefficient order (p sequential -> batched s_loads).
    // c is wave-uniform: the single SGPR operand of v_fmac_f32.
    float acc = 0.0f;
    int p = 0;
#pragma unroll
    for (int k = 1; k < KF; ++k) {
        float w = 0.0f;
#pragma unroll
        for (int l = 0; l < k; ++l) {
            w = fmaf(c[p++], v[l], w);
        }
        acc = fmaf(v[k], w, acc);
    }

    out[n] = acc;   // 0.5 already folded into c
}

extern "C" void kernel_launch(void* const* d_in, const int* in_sizes, int n_in,
                              void* d_out, int out_size, void* d_ws, size_t ws_size,
                              hipStream_t stream) {
    const float* x = (const float*)d_in[0];          // [39, 8192, 64]
    const float* W = (const float*)d_in[1];          // [39, 39]
    float* out = (float*)d_out;                      // [8192, 64]
    float* coef = (float*)d_ws;                      // 741 floats of scratch

    fwfm_coef_kernel<<<(KF * KF + 255) / 256, 256, 0, stream>>>(W, coef);
    fwfm_kernel<<<NELEM / 256, 256, 0, stream>>>(x, coef, out);
}